// Round 16
// baseline (450.735 us; speedup 1.0000x reference)
//
#include <hip/hip_runtime.h>

#define B_   256
#define HID  512
#define T_   32
#define L_   256
#define NC   97
#define G4   2048

// d_out layout (f32): g [256,32,97] | output_hiddens [256,32,512] | masks [256,32,8,32]
#define OH_OFF   794624
#define MASK_OFF 4988928

typedef __bf16 v8bf __attribute__((ext_vector_type(8)));
typedef float  v4f  __attribute__((ext_vector_type(4)));
typedef unsigned int v4u __attribute__((ext_vector_type(4)));

__device__ __forceinline__ unsigned short f2bf(float x){
  unsigned u = __float_as_uint(x);
  u += 0x7FFFu + ((u >> 16) & 1u);          // round-to-nearest-even
  return (unsigned short)(u >> 16);
}
__device__ __forceinline__ float bf2f(unsigned short h){
  return __uint_as_float(((unsigned)h) << 16);
}
__device__ __forceinline__ float sigm(float x){ return 1.f / (1.f + __expf(-x)); }
__device__ __forceinline__ float tanh_f(float x){
  float e = __expf(2.f * x);
  return 1.f - 2.f / (e + 1.f);             // safe at +/-inf
}
__device__ __forceinline__ v8bf ld8(const unsigned short* p){
  return *reinterpret_cast<const v8bf*>(p);
}

// ---------------------------------------------------------------- one-time --
__global__ void k_wconv(const float* __restrict__ Whh0, const float* __restrict__ Wih1,
                        const float* __restrict__ Whh1, const float* __restrict__ Wih0,
                        unsigned short* __restrict__ Whh0bf, unsigned short* __restrict__ Wcat1bf,
                        unsigned short* __restrict__ Wih0bf){
  int i = blockIdx.x * 256 + threadIdx.x;
  if (i >= G4 * HID) return;
  Whh0bf[i] = f2bf(Whh0[i]);
  Wih0bf[i] = f2bf(Wih0[i]);
  int n = i >> 9, k = i & 511;
  Wcat1bf[(size_t)n * 1024 + k]       = f2bf(Wih1[i]);
  Wcat1bf[(size_t)n * 1024 + 512 + k] = f2bf(Whh1[i]);
}

__global__ void k_small(const float* __restrict__ embW, const float* __restrict__ embb,
                        const float* __restrict__ genW, const float* __restrict__ bih1,
                        const float* __restrict__ bhh1,
                        unsigned short* __restrict__ embXbf, unsigned short* __restrict__ genWbf,
                        float* __restrict__ b1sum){
  int i = blockIdx.x * 256 + threadIdx.x;
  if (i < NC * HID){
    int c = i >> 9, h = i & 511;
    embXbf[i] = f2bf(embW[h * NC + c] + embb[h]);
    genWbf[i] = f2bf(genW[i]);
  }
  if (i < G4) b1sum[i] = bih1[i] + bhh1[i];
}

// emb_gates[c][n] (MFMA, M=97 N=2048 K=512)
__global__ void __launch_bounds__(64)
k_embg_m(const unsigned short* __restrict__ embXbf, const unsigned short* __restrict__ Wih0bf,
         const float* __restrict__ bih0, const float* __restrict__ bhh0,
         float* __restrict__ embg){
  int m0 = blockIdx.x * 16, j0 = blockIdx.y * 16;
  int l = threadIdx.x, lr = l & 15, lk = l >> 4;
  int ar = min(m0 + lr, NC - 1);
  v4f acc = {0,0,0,0};
  for (int ks = 0; ks < 16; ++ks){
    int kb = ks * 32 + lk * 8;
    v8bf a  = ld8(embXbf + (size_t)ar * HID + kb);
    v8bf bf = ld8(Wih0bf + (size_t)(j0 + lr) * HID + kb);
    acc = __builtin_amdgcn_mfma_f32_16x16x32_bf16(a, bf, acc, 0, 0, 0);
  }
  int n = j0 + lr;
  float bb = bih0[n] + bhh0[n];
#pragma unroll
  for (int r = 0; r < 4; ++r){
    int c = m0 + lk * 4 + r;
    if (c < NC) embg[(size_t)c * G4 + n] = acc[r] + bb;
  }
}

// origin[b][c][l] f32 -> fmapT[b][l][c] bf16
__global__ void k_fmapT(const float* __restrict__ orig, unsigned short* __restrict__ fT){
  __shared__ float tile[32][33];
  int b = blockIdx.z, c0 = blockIdx.y * 32, l0 = blockIdx.x * 32;
  const float* src = orig + ((size_t)b * HID + c0) * L_ + l0;
  for (int i = 0; i < 32; i += 8)
    tile[threadIdx.y + i][threadIdx.x] = src[(threadIdx.y + i) * L_ + threadIdx.x];
  __syncthreads();
  unsigned short* dst = fT + ((size_t)b * L_ + l0) * HID + c0;
  for (int i = 0; i < 32; i += 8)
    dst[(threadIdx.y + i) * HID + threadIdx.x] = f2bf(tile[threadIdx.x][threadIdx.y + i]);
}

// --------------------------- persistent gate-split pipelined LSTM (coop) ----
// 1024 blocks x 256 thr, ~39KB LDS, 4 blocks/CU. Per-band per-chain sync
// (round 15) with round-16 refinement: DIRECT 32-flag polling by every
// consumer block (lane i polls producer i's flag in parallel) -- deletes the
// leader-aggregate + release MALL round trip from the critical path.
// A(band,jg): wait all band-A flags >= p, compute h0(p+1), flag = p+1.
// B(band,jg): wait band-A flags >= p (h0(p) ready) AND band-B flags >= p-1
// (h1(p-1) ready), compute h1(p), flag = p. Flag stores issue after
// __syncthreads drains write-through h-stores (flag visible => h visible);
// readers use plain loads on virgin ring lines. Weights in VGPR (round 14).
__global__ void __launch_bounds__(256, 4)
k_loop3(const unsigned short* __restrict__ Whh0bf,
        const unsigned short* __restrict__ Wcat1bf,
        const float* __restrict__ embg, const int* __restrict__ text,
        const float* __restrict__ b1sum,
        unsigned short* h0r, unsigned short* h1r,
        unsigned int* flags){
  const int SLOT = B_ * HID;
  const int bid = blockIdx.x;
  const bool isB = bid >= 512;
  const int gb = bid & 511;
  const int band = gb >> 5, jg = gb & 31;
  const int m0 = band * 16, j0 = jg * 16;
  const int tid = threadIdx.x;
  const int w = tid >> 6, l = tid & 63, lr = l & 15, lk = l >> 4;

  __shared__ unsigned short hS[16][1048];
  __shared__ float gbuf[4][16][17];
  __shared__ unsigned tS[16][32];            // text[row][t] * G4 (A blocks)

  const int erow = tid >> 4, ecol = tid & 15;      // epilogue element
  const int ebrow = m0 + erow, ej = j0 + ecol;
  float creg = 0.f;                                // c-state, 1 VGPR
  float xb0 = 0.f, xb1 = 0.f, xb2 = 0.f, xb3 = 0.f;
  if (isB){
    xb0 = b1sum[ej]; xb1 = b1sum[512 + ej];
    xb2 = b1sum[1024 + ej]; xb3 = b1sum[1536 + ej];
  } else {
    for (int e = tid; e < 512; e += 256)
      tS[e >> 5][e & 31] = (unsigned)text[(m0 + (e >> 5)) * T_ + (e & 31)] * G4;
  }
  const unsigned short* W = isB ? Wcat1bf : Whh0bf;
  const int wstr = isB ? 1024 : 512;
  const unsigned short* wrow = W + (size_t)(w * HID + j0 + lr) * wstr;

  // ---- hoist phase-invariant weights into registers
  v8bf wreg[16];                             // A: all 16; B: ks 24..31 in [8..15]
  if (!isB){
#pragma unroll
    for (int i = 0; i < 16; ++i) wreg[i] = ld8(wrow + i * 32 + lk * 8);
  } else {
#pragma unroll
    for (int i = 8; i < 16; ++i) wreg[i] = ld8(wrow + (16 + i) * 32 + lk * 8);
  }

  if (!isB){
    // =================== A chain: phases 0..31 =============================
    for (int p = 0; p < 32; ++p){
      if (p >= 1){
        if (tid < 32){
          const unsigned* fp = &flags[(band * 32 + tid) * 16];
          unsigned it = 0;
          while (__hip_atomic_load(fp, __ATOMIC_RELAXED,
                                   __HIP_MEMORY_SCOPE_AGENT) < (unsigned)p){
            if (++it > 2000000u) break;
            __builtin_amdgcn_s_sleep(1);
          }
        }
        __syncthreads();
        asm volatile("" ::: "memory");
      }
      const unsigned short* hA = h0r + (size_t)p * SLOT;
#pragma unroll
      for (int i = 0; i < 4; ++i){
        int e = tid + 256 * i;               // 0..1023 16B chunks
        int row = e >> 6, c8 = (e & 63) * 8;
        *(v4u*)&hS[row][c8] = *(const v4u*)(hA + (size_t)(m0 + row) * HID + c8);
      }
      __syncthreads();
      v4f acc = {0,0,0,0};
#pragma unroll
      for (int ks = 0; ks < 16; ++ks){
        v8bf a = *(const v8bf*)&hS[lr][ks * 32 + lk * 8];
        acc = __builtin_amdgcn_mfma_f32_16x16x32_bf16(a, wreg[ks], acc, 0, 0, 0);
      }
#pragma unroll
      for (int r = 0; r < 4; ++r)
        gbuf[w][lk * 4 + r][lr] = acc[r];
      __syncthreads();
      {
        const float* eg = embg + (size_t)tS[erow][p] + ej;
        float xi = eg[0], xf = eg[512], xg = eg[1024], xo = eg[1536];
        float ig = gbuf[0][erow][ecol] + xi, fg = gbuf[1][erow][ecol] + xf;
        float gg = gbuf[2][erow][ecol] + xg, og = gbuf[3][erow][ecol] + xo;
        float cn = sigm(fg) * creg + sigm(ig) * tanh_f(gg);
        creg = cn;
        float hn = sigm(og) * tanh_f(cn);
        unsigned short* hout = h0r + (size_t)(p + 1) * SLOT;
        unsigned v = f2bf(hn);
        unsigned pv = (unsigned)__shfl_xor((int)v, 1);
        if (!(tid & 1)){
          unsigned pack = (v & 0xFFFFu) | (pv << 16);
          __hip_atomic_store((unsigned*)(hout + (size_t)ebrow * HID + ej), pack,
                             __ATOMIC_RELAXED, __HIP_MEMORY_SCOPE_AGENT);
        }
      }
      __syncthreads();                       // drain h-stores; protect hS/gbuf
      if (tid == 0)
        __hip_atomic_store(&flags[bid * 16], (unsigned)(p + 1),
                           __ATOMIC_RELAXED, __HIP_MEMORY_SCOPE_AGENT);
    }
  } else {
    // =================== B chain: phases 1..32 =============================
    for (int p = 1; p <= 32; ++p){
      if (tid < 32){
        const unsigned* fp = &flags[(band * 32 + tid) * 16];       // A flags
        unsigned it = 0;
        while (__hip_atomic_load(fp, __ATOMIC_RELAXED,
                                 __HIP_MEMORY_SCOPE_AGENT) < (unsigned)p){
          if (++it > 2000000u) break;
          __builtin_amdgcn_s_sleep(1);
        }
      } else if (tid < 64 && p >= 2){
        const unsigned* fp = &flags[(512 + band * 32 + (tid - 32)) * 16]; // B flags
        unsigned it = 0;
        while (__hip_atomic_load(fp, __ATOMIC_RELAXED,
                                 __HIP_MEMORY_SCOPE_AGENT) < (unsigned)(p - 1)){
          if (++it > 2000000u) break;
          __builtin_amdgcn_s_sleep(1);
        }
      }
      __syncthreads();
      asm volatile("" ::: "memory");
      const unsigned short* hA = h0r + (size_t)p * SLOT;        // h0(p)
      const unsigned short* hB = h1r + (size_t)(p - 1) * SLOT;  // h1(p-1)
#pragma unroll
      for (int i = 0; i < 8; ++i){
        int e = tid + 256 * i;               // 0..2047 16B chunks
        int part = e >> 10, ei = e & 1023;
        int row = ei >> 6, c8 = (ei & 63) * 8;
        const unsigned short* src = (part ? hB : hA) + (size_t)(m0 + row) * HID + c8;
        *(v4u*)&hS[row][part * 512 + c8] = *(const v4u*)src;
      }
      __syncthreads();
      v4f acc = {0,0,0,0};
#pragma unroll
      for (int ks = 0; ks < 24; ++ks){
        v8bf bf = ld8(wrow + ks * 32 + lk * 8);
        v8bf a  = *(const v8bf*)&hS[lr][ks * 32 + lk * 8];
        acc = __builtin_amdgcn_mfma_f32_16x16x32_bf16(a, bf, acc, 0, 0, 0);
      }
#pragma unroll
      for (int i = 8; i < 16; ++i){
        v8bf a = *(const v8bf*)&hS[lr][(16 + i) * 32 + lk * 8];
        acc = __builtin_amdgcn_mfma_f32_16x16x32_bf16(a, wreg[i], acc, 0, 0, 0);
      }
#pragma unroll
      for (int r = 0; r < 4; ++r)
        gbuf[w][lk * 4 + r][lr] = acc[r];
      __syncthreads();
      {
        float ig = gbuf[0][erow][ecol] + xb0, fg = gbuf[1][erow][ecol] + xb1;
        float gg = gbuf[2][erow][ecol] + xb2, og = gbuf[3][erow][ecol] + xb3;
        float cn = sigm(fg) * creg + sigm(ig) * tanh_f(gg);
        creg = cn;
        float hn = sigm(og) * tanh_f(cn);
        unsigned short* hout = h1r + (size_t)p * SLOT;          // h1(p)
        unsigned v = f2bf(hn);
        unsigned pv = (unsigned)__shfl_xor((int)v, 1);
        if (!(tid & 1)){
          unsigned pack = (v & 0xFFFFu) | (pv << 16);
          __hip_atomic_store((unsigned*)(hout + (size_t)ebrow * HID + ej), pack,
                             __ATOMIC_RELAXED, __HIP_MEMORY_SCOPE_AGENT);
        }
      }
      __syncthreads();                       // drain h-stores; protect hS/gbuf
      if (tid == 0)
        __hip_atomic_store(&flags[(512 + band * 32 + jg) * 16], (unsigned)p,
                           __ATOMIC_RELAXED, __HIP_MEMORY_SCOPE_AGENT);
    }
  }
}

// -------------------------------------- fallback: fused per-step launches ---
__global__ void __launch_bounds__(256)
k_step2(const unsigned short* __restrict__ Whh0bf,
        const unsigned short* __restrict__ Wcat1bf,
        const float* __restrict__ embg, const int* __restrict__ text,
        const float* __restrict__ b1sum,
        unsigned short* __restrict__ h0r, unsigned short* __restrict__ h1r,
        float* __restrict__ c0, float* __restrict__ c1, int p){
  const int SLOT = B_ * HID;
  const int bid = blockIdx.x;
  const bool isB = bid >= 512;
  if (isB ? (p < 1) : (p >= 32)) return;
  const int gb = bid & 511;
  const int band = gb >> 5, jg = gb & 31;
  const int m0 = band * 16, j0 = jg * 16;
  const int tid = threadIdx.x;
  const int w = tid >> 6, l = tid & 63, lr = l & 15, lk = l >> 4;
  const int t = isB ? (p - 1) : p;

  __shared__ unsigned short hS[16][1048];
  __shared__ float gbuf[4][16][17];

  const unsigned short* hA = h0r + (size_t)p * SLOT;
  const unsigned short* hB = h1r + (size_t)(isB ? (p - 1) : 0) * SLOT;

  if (isB){
#pragma unroll
    for (int i = 0; i < 8; ++i){
      int e = tid + 256 * i;
      int part = e >> 10, ei = e & 1023;
      int row = ei >> 6, c8 = (ei & 63) * 8;
      const unsigned short* src = (part ? hB : hA) + (size_t)(m0 + row) * HID + c8;
      *(v4u*)&hS[row][part * 512 + c8] = *(const v4u*)src;
    }
  } else {
#pragma unroll
    for (int i = 0; i < 4; ++i){
      int e = tid + 256 * i;
      int row = e >> 6, c8 = (e & 63) * 8;
      *(v4u*)&hS[row][c8] = *(const v4u*)(hA + (size_t)(m0 + row) * HID + c8);
    }
  }
  __syncthreads();

  const unsigned short* W = isB ? Wcat1bf : Whh0bf;
  const int wstr = isB ? 1024 : 512;
  const int KS   = isB ? 32 : 16;
  const unsigned short* wrow = W + (size_t)(w * HID + j0 + lr) * wstr;
  v4f acc = {0,0,0,0};
#pragma unroll 4
  for (int ks = 0; ks < KS; ++ks){
    const int kb = ks * 32 + lk * 8;
    v8bf a  = *(const v8bf*)&hS[lr][kb];
    v8bf bf = ld8(wrow + kb);
    acc = __builtin_amdgcn_mfma_f32_16x16x32_bf16(a, bf, acc, 0, 0, 0);
  }
#pragma unroll
  for (int r = 0; r < 4; ++r)
    gbuf[w][lk * 4 + r][lr] = acc[r];
  __syncthreads();

  {
    const int row = tid >> 4, col = tid & 15;
    const int brow = m0 + row, j = j0 + col;
    float xi, xf, xg, xo;
    if (!isB){
      const float* eg = embg + (size_t)text[brow * T_ + t] * G4 + j;
      xi = eg[0]; xf = eg[512]; xg = eg[1024]; xo = eg[1536];
    } else {
      xi = b1sum[j]; xf = b1sum[512 + j];
      xg = b1sum[1024 + j]; xo = b1sum[1536 + j];
    }
    float ig = gbuf[0][row][col] + xi, fg = gbuf[1][row][col] + xf;
    float gg = gbuf[2][row][col] + xg, og = gbuf[3][row][col] + xo;
    float* cst = isB ? c1 : c0;
    size_t ci = (size_t)brow * HID + j;
    float cn = sigm(fg) * cst[ci] + sigm(ig) * tanh_f(gg);
    cst[ci] = cn;
    float hn = sigm(og) * tanh_f(cn);
    unsigned short* hout = isB ? (h1r + (size_t)p * SLOT)
                               : (h0r + (size_t)(p + 1) * SLOT);
    unsigned v = f2bf(hn);
    unsigned pv = (unsigned)__shfl_xor((int)v, 1);
    if (!(tid & 1)){
      unsigned pack = (v & 0xFFFFu) | (pv << 16);
      *(unsigned*)(hout + (size_t)brow * HID + j) = pack;
    }
  }
}

// --------------------------------------- fused single-pass attention -------
// One block per batch, 512 thr (8 waves). Per 64-l tile: MFMA S (h1 frags in
// VGPR) -> sigmoid -> masks + aS LDS -> immediate VALU context accumulation
// with f rows L2-hot. fmapT is read ~once (2nd touch L2) vs twice from L3.
__global__ void __launch_bounds__(512)
k_attn(const unsigned short* __restrict__ fT, const unsigned short* __restrict__ h1r,
       float* __restrict__ d_out, unsigned short* __restrict__ ctxbf){
  int b = blockIdx.x, tid = threadIdx.x, w = tid >> 6, l = tid & 63;
  int lr = l & 15, lk = l >> 4;
  int mh = w >> 2, nq = w & 3;
  __shared__ float aS[32][65];
  const unsigned short* fb = fT + (size_t)b * L_ * HID;
  // preload h1 fragments: rows t = mh*16 + lr (ring slot t+1)
  v8bf afr[16];
#pragma unroll
  for (int ks = 0; ks < 16; ++ks)
    afr[ks] = ld8(h1r + ((size_t)(mh * 16 + lr + 1) * B_ + b) * HID + ks * 32 + lk * 8);
  float vacc[4][8] = {};
  for (int it = 0; it < 4; ++it){
    v4f acc = {0,0,0,0};
#pragma unroll
    for (int ks = 0; ks < 16; ++ks){
      v8bf bf = ld8(fb + (size_t)(it * 64 + nq * 16 + lr) * HID + ks * 32 + lk * 8);
      acc = __builtin_amdgcn_mfma_f32_16x16x32_bf16(afr[ks], bf, acc, 0, 0, 0);
    }
#pragma unroll
    for (int r = 0; r < 4; ++r){
      int tt = mh * 16 + lk * 4 + r;
      int li = nq * 16 + lr;
      float aa = sigm(acc[r]);
      d_out[MASK_OFF + ((size_t)b * T_ + tt) * L_ + it * 64 + li] = aa;
      aS[tt][li] = aa;
    }
    __syncthreads();
#pragma unroll 4
    for (int li = 0; li < 64; ++li){
      const unsigned short* fr = fb + (size_t)(it * 64 + li) * HID + l * 8;
      ushort4 u0 = *(const ushort4*)fr;
      ushort4 u1 = *(const ushort4*)(fr + 4);
      float f[8] = {bf2f(u0.x), bf2f(u0.y), bf2f(u0.z), bf2f(u0.w),
                    bf2f(u1.x), bf2f(u1.y), bf2f(u1.z), bf2f(u1.w)};
#pragma unroll
      for (int tt = 0; tt < 4; ++tt){
        float a = aS[w * 4 + tt][li];
#pragma unroll
        for (int k = 0; k < 8; ++k) vacc[tt][k] += a * f[k];
      }
    }
    __syncthreads();                         // aS reuse next tile
  }
#pragma unroll
  for (int tt = 0; tt < 4; ++tt)
#pragma unroll
    for (int k = 0; k < 8; ++k){
      size_t o = ((size_t)b * T_ + w * 4 + tt) * HID + l * 8 + k;
      d_out[OH_OFF + o] = vacc[tt][k];
      ctxbf[o] = f2bf(vacc[tt][k]);
    }
}

// ------------------------------------------------------------------ final ---
__global__ void __launch_bounds__(256)
k_gen_m(const unsigned short* __restrict__ ctxbf, const unsigned short* __restrict__ genWbf,
        const float* __restrict__ genb, float* __restrict__ g){
  int m0 = blockIdx.x * 64 + (threadIdx.x >> 6) * 16;
  int j0 = blockIdx.y * 16;
  int l = threadIdx.x & 63, lr = l & 15, lk = l >> 4;
  int n = j0 + lr, nr = min(n, NC - 1);
  v4f acc = {0,0,0,0};
  for (int ks = 0; ks < 16; ++ks){
    int kb = ks * 32 + lk * 8;
    v8bf a  = ld8(ctxbf + (size_t)(m0 + lr) * HID + kb);
    v8bf bf = ld8(genWbf + (size_t)nr * HID + kb);
    acc = __builtin_amdgcn_mfma_f32_16x16x32_bf16(a, bf, acc, 0, 0, 0);
  }
  if (n < NC){
    float bb = genb[n];
#pragma unroll
    for (int r = 0; r < 4; ++r)
      g[(size_t)(m0 + lk * 4 + r) * NC + n] = acc[r] + bb;
  }
}

// --------------------------------------------------------------- fallbacks --
__global__ void __launch_bounds__(256)
k_attn_direct(const float* __restrict__ orig, const unsigned short* __restrict__ h1b,
              float* __restrict__ d_out, int t){
  int b = blockIdx.x, tid = threadIdx.x;
  __shared__ float h1s[HID];
  __shared__ float as[L_];
  h1s[tid]       = bf2f(h1b[(size_t)b * HID + tid]);
  h1s[256 + tid] = bf2f(h1b[(size_t)b * HID + 256 + tid]);
  __syncthreads();
  const float* fb = orig + (size_t)b * HID * L_;
  float dot = 0.f;
  for (int ch = 0; ch < HID; ++ch) dot += h1s[ch] * fb[(size_t)ch * L_ + tid];
  float a = sigm(dot);
  as[tid] = a;
  d_out[MASK_OFF + ((size_t)b * T_ + t) * L_ + tid] = a;
  __syncthreads();
  for (int cc = 0; cc < 2; ++cc){
    int ch = tid + cc * 256;
    float s = 0.f;
    for (int ll = 0; ll < L_; ++ll) s += as[ll] * fb[(size_t)ch * L_ + ll];
    d_out[OH_OFF + ((size_t)b * T_ + t) * HID + ch] = s;
  }
}

__global__ void k_gen_v(const float* __restrict__ ctx, const float* __restrict__ genW,
                        const float* __restrict__ genb, float* __restrict__ g){
  int o = blockIdx.x * 256 + threadIdx.x;
  if (o >= B_ * T_ * NC) return;
  int m = o / NC, n = o - m * NC;
  const float4* a = (const float4*)(ctx + (size_t)m * HID);
  const float4* wv = (const float4*)(genW + (size_t)n * HID);
  float s = genb[n];
  for (int k = 0; k < HID / 4; ++k){
    float4 av = a[k], w = wv[k];
    s += av.x * w.x + av.y * w.y + av.z * w.z + av.w * w.w;
  }
  g[o] = s;
}

// -----------------------------------------------------------------------------
extern "C" void kernel_launch(void* const* d_in, const int* in_sizes, int n_in,
                              void* d_out, int out_size, void* d_ws, size_t ws_size,
                              hipStream_t stream){
  const float* orig = (const float*)d_in[0];
  const int*   text = (const int*)  d_in[1];
  const float* embW = (const float*)d_in[2];
  const float* embb = (const float*)d_in[3];
  const float* Wih0 = (const float*)d_in[4];
  const float* Whh0 = (const float*)d_in[5];
  const float* bih0 = (const float*)d_in[6];
  const float* bhh0 = (const float*)d_in[7];
  const float* Wih1 = (const float*)d_in[8];
  const float* Whh1 = (const float*)d_in[9];
  const float* bih1 = (const float*)d_in[10];
  const float* bhh1 = (const float*)d_in[11];
  const float* genW = (const float*)d_in[12];
  const float* genb = (const float*)d_in[13];
  float* out = (float*)d_out;

  const size_t SLOTB = (size_t)B_ * HID * 2;          // 256 KB

  char* p = (char*)d_ws;
  float* embg  = (float*)p;           p += (size_t)NC * G4 * 4;
  float* b1sum = (float*)p;           p += (size_t)G4 * 4;
  // ---- zero-init region (c-state + flags) ----
  float* c0 = (float*)p;                       p += (size_t)B_ * HID * 4;
  float* c1 = (float*)p;                       p += (size_t)B_ * HID * 4;
  unsigned int* flags = (unsigned int*)p;      p += 1024 * 64;      // 1 line/block
  size_t zbytes = (size_t)((char*)p - (char*)c0);
  // ---- end zero region ----
  unsigned short* Whh0bf  = (unsigned short*)p; p += (size_t)G4 * 512 * 2;
  unsigned short* Wcat1bf = (unsigned short*)p; p += (size_t)G4 * 1024 * 2;
  unsigned short* Wih0bf  = (unsigned short*)p; p += (size_t)G4 * 512 * 2;
  unsigned short* embXbf  = (unsigned short*)p; p += (size_t)NC * HID * 2;
  unsigned short* genWbf  = (unsigned short*)p; p += (size_t)NC * HID * 2;
  unsigned short* h0r = (unsigned short*)p;    p += 34 * SLOTB;     // h0 ring (8.5MB)
  unsigned short* h1r = (unsigned short*)p;    p += 33 * SLOTB;     // h1 ring (8.25MB)
  unsigned short* ctxbf = (unsigned short*)p;  p += (size_t)B_ * T_ * HID * 2;  // 8MB
  unsigned short* fmapT = (unsigned short*)p;  p += (size_t)B_ * L_ * HID * 2;  // 64MB
  bool big = ws_size >= (size_t)(p - (char*)d_ws);

  hipMemsetAsync(c0, 0, zbytes, stream);
  hipMemsetAsync(h0r, 0, SLOTB, stream);              // h0(0) = zeros
  hipMemsetAsync(h1r, 0, SLOTB, stream);              // h1(0) = zeros

  k_wconv<<<(G4 * HID + 255) / 256, 256, 0, stream>>>(Whh0, Wih1, Whh1, Wih0,
                                                      Whh0bf, Wcat1bf, Wih0bf);
  k_small<<<(NC * HID + 255) / 256, 256, 0, stream>>>(embW, embb, genW, bih1, bhh1,
                                                      embXbf, genWbf, b1sum);
  k_embg_m<<<dim3(7, G4 / 16), 64, 0, stream>>>(embXbf, Wih0bf, bih0, bhh0, embg);
  if (big) k_fmapT<<<dim3(L_ / 32, HID / 32, B_), dim3(32, 8), 0, stream>>>(orig, fmapT);

  // ---- the recurrence: single persistent cooperative dispatch ----
  hipError_t ce = hipErrorUnknown;
  if (big){
    const unsigned short* a0 = Whh0bf; const unsigned short* a1 = Wcat1bf;
    const float* a2 = embg; const int* a3 = text; const float* a4 = b1sum;
    unsigned short* a5 = h0r; unsigned short* a6 = h1r;
    unsigned int* a7 = flags;
    void* args[] = {&a0, &a1, &a2, &a3, &a4, &a5, &a6, &a7};
    ce = hipLaunchCooperativeKernel((const void*)k_loop3, dim3(1024), dim3(256),
                                    args, 0, stream);
  }
  if (ce != hipSuccess){
    // fallback: proven 33-launch chain (round-11 path, ring buffers)
    for (int pp = 0; pp <= 32; ++pp)
      k_step2<<<1024, 256, 0, stream>>>(Whh0bf, Wcat1bf, embg, text, b1sum,
                                        h0r, h1r, c0, c1, pp);
  }

  if (big){
    k_attn<<<B_, 512, 0, stream>>>(fmapT, h1r, out, ctxbf);
    k_gen_m<<<dim3(B_ * T_ / 64, 7), 256, 0, stream>>>(ctxbf, genWbf, genb, out);
  } else {
    for (int t = 0; t < T_; ++t)
      k_attn_direct<<<B_, 256, 0, stream>>>(orig, h1r + (size_t)(t + 1) * B_ * HID,
                                            out, t);
    k_gen_v<<<(B_ * T_ * NC + 255) / 256, 256, 0, stream>>>(out + OH_OFF, genW, genb, out);
  }
}

// Round 17
// 433.488 us; speedup vs baseline: 1.0398x; 1.0398x over previous
//
#include <hip/hip_runtime.h>

#define B_   256
#define HID  512
#define T_   32
#define L_   256
#define NC   97
#define G4   2048

// d_out layout (f32): g [256,32,97] | output_hiddens [256,32,512] | masks [256,32,8,32]
#define OH_OFF   794624
#define MASK_OFF 4988928

typedef __bf16 v8bf __attribute__((ext_vector_type(8)));
typedef float  v4f  __attribute__((ext_vector_type(4)));
typedef unsigned int v4u __attribute__((ext_vector_type(4)));

__device__ __forceinline__ unsigned short f2bf(float x){
  unsigned u = __float_as_uint(x);
  u += 0x7FFFu + ((u >> 16) & 1u);          // round-to-nearest-even
  return (unsigned short)(u >> 16);
}
__device__ __forceinline__ float bf2f(unsigned short h){
  return __uint_as_float(((unsigned)h) << 16);
}
__device__ __forceinline__ float sigm(float x){ return 1.f / (1.f + __expf(-x)); }
__device__ __forceinline__ float tanh_f(float x){
  float e = __expf(2.f * x);
  return 1.f - 2.f / (e + 1.f);             // safe at +/-inf
}
__device__ __forceinline__ v8bf ld8(const unsigned short* p){
  return *reinterpret_cast<const v8bf*>(p);
}

// ---------------------------------------------------------------- one-time --
__global__ void k_wconv(const float* __restrict__ Whh0, const float* __restrict__ Wih1,
                        const float* __restrict__ Whh1, const float* __restrict__ Wih0,
                        unsigned short* __restrict__ Whh0bf, unsigned short* __restrict__ Wcat1bf,
                        unsigned short* __restrict__ Wih0bf){
  int i = blockIdx.x * 256 + threadIdx.x;
  if (i >= G4 * HID) return;
  Whh0bf[i] = f2bf(Whh0[i]);
  Wih0bf[i] = f2bf(Wih0[i]);
  int n = i >> 9, k = i & 511;
  Wcat1bf[(size_t)n * 1024 + k]       = f2bf(Wih1[i]);
  Wcat1bf[(size_t)n * 1024 + 512 + k] = f2bf(Whh1[i]);
}

__global__ void k_small(const float* __restrict__ embW, const float* __restrict__ embb,
                        const float* __restrict__ genW, const float* __restrict__ bih1,
                        const float* __restrict__ bhh1,
                        unsigned short* __restrict__ embXbf, unsigned short* __restrict__ genWbf,
                        float* __restrict__ b1sum){
  int i = blockIdx.x * 256 + threadIdx.x;
  if (i < NC * HID){
    int c = i >> 9, h = i & 511;
    embXbf[i] = f2bf(embW[h * NC + c] + embb[h]);
    genWbf[i] = f2bf(genW[i]);
  }
  if (i < G4) b1sum[i] = bih1[i] + bhh1[i];
}

// emb_gates[c][n] (MFMA, M=97 N=2048 K=512)
__global__ void __launch_bounds__(64)
k_embg_m(const unsigned short* __restrict__ embXbf, const unsigned short* __restrict__ Wih0bf,
         const float* __restrict__ bih0, const float* __restrict__ bhh0,
         float* __restrict__ embg){
  int m0 = blockIdx.x * 16, j0 = blockIdx.y * 16;
  int l = threadIdx.x, lr = l & 15, lk = l >> 4;
  int ar = min(m0 + lr, NC - 1);
  v4f acc = {0,0,0,0};
  for (int ks = 0; ks < 16; ++ks){
    int kb = ks * 32 + lk * 8;
    v8bf a  = ld8(embXbf + (size_t)ar * HID + kb);
    v8bf bf = ld8(Wih0bf + (size_t)(j0 + lr) * HID + kb);
    acc = __builtin_amdgcn_mfma_f32_16x16x32_bf16(a, bf, acc, 0, 0, 0);
  }
  int n = j0 + lr;
  float bb = bih0[n] + bhh0[n];
#pragma unroll
  for (int r = 0; r < 4; ++r){
    int c = m0 + lk * 4 + r;
    if (c < NC) embg[(size_t)c * G4 + n] = acc[r] + bb;
  }
}

// origin[b][c][l] f32 -> fmapT[b][l][c] bf16
__global__ void k_fmapT(const float* __restrict__ orig, unsigned short* __restrict__ fT){
  __shared__ float tile[32][33];
  int b = blockIdx.z, c0 = blockIdx.y * 32, l0 = blockIdx.x * 32;
  const float* src = orig + ((size_t)b * HID + c0) * L_ + l0;
  for (int i = 0; i < 32; i += 8)
    tile[threadIdx.y + i][threadIdx.x] = src[(threadIdx.y + i) * L_ + threadIdx.x];
  __syncthreads();
  unsigned short* dst = fT + ((size_t)b * L_ + l0) * HID + c0;
  for (int i = 0; i < 32; i += 8)
    dst[(threadIdx.y + i) * HID + threadIdx.x] = f2bf(tile[threadIdx.x][threadIdx.y + i]);
}

// --------------------------- persistent gate-split pipelined LSTM (coop) ----
// 1024 blocks x 256 thr, ~39KB LDS, 4 blocks/CU. Per-band direct-poll sync
// (rounds 15/16). Round-17 change: B-chain PRE/CRIT K-SPLIT. Only the
// ks 16..31 half of B's MFMA depends on h1(p-1); the ks 0..15 half multiplies
// h0(p), which A (running ahead) produced long ago. So per phase:
//   PRE : poll A flags >= p (instant), stage h0(p), MFMA ks 0..15 -> acc
//   CRIT: poll B flags >= p-1 (visibility latency HIDDEN under PRE),
//         stage h1(p-1), MFMA ks 16..31, epilogue, store h1(p), flag.
// The B->B critical path loses h0 staging + half the MFMA + the naked wait.
__global__ void __launch_bounds__(256, 4)
k_loop3(const unsigned short* __restrict__ Whh0bf,
        const unsigned short* __restrict__ Wcat1bf,
        const float* __restrict__ embg, const int* __restrict__ text,
        const float* __restrict__ b1sum,
        unsigned short* h0r, unsigned short* h1r,
        unsigned int* flags){
  const int SLOT = B_ * HID;
  const int bid = blockIdx.x;
  const bool isB = bid >= 512;
  const int gb = bid & 511;
  const int band = gb >> 5, jg = gb & 31;
  const int m0 = band * 16, j0 = jg * 16;
  const int tid = threadIdx.x;
  const int w = tid >> 6, l = tid & 63, lr = l & 15, lk = l >> 4;

  __shared__ unsigned short hS[16][1048];
  __shared__ float gbuf[4][16][17];
  __shared__ unsigned tS[16][32];            // text[row][t] * G4 (A blocks)

  const int erow = tid >> 4, ecol = tid & 15;      // epilogue element
  const int ebrow = m0 + erow, ej = j0 + ecol;
  float creg = 0.f;                                // c-state, 1 VGPR
  float xb0 = 0.f, xb1 = 0.f, xb2 = 0.f, xb3 = 0.f;
  if (isB){
    xb0 = b1sum[ej]; xb1 = b1sum[512 + ej];
    xb2 = b1sum[1024 + ej]; xb3 = b1sum[1536 + ej];
  } else {
    for (int e = tid; e < 512; e += 256)
      tS[e >> 5][e & 31] = (unsigned)text[(m0 + (e >> 5)) * T_ + (e & 31)] * G4;
  }
  const unsigned short* W = isB ? Wcat1bf : Whh0bf;
  const int wstr = isB ? 1024 : 512;
  const unsigned short* wrow = W + (size_t)(w * HID + j0 + lr) * wstr;

  // ---- hoist phase-invariant weights (A: all 16 ks; B: crit half ks 16..31)
  v8bf wreg[16];
  if (!isB){
#pragma unroll
    for (int i = 0; i < 16; ++i) wreg[i] = ld8(wrow + i * 32 + lk * 8);
  } else {
#pragma unroll
    for (int i = 0; i < 16; ++i) wreg[i] = ld8(wrow + (16 + i) * 32 + lk * 8);
  }

  if (!isB){
    // =================== A chain: phases 0..31 =============================
    for (int p = 0; p < 32; ++p){
      if (p >= 1){
        if (tid < 32){
          const unsigned* fp = &flags[(band * 32 + tid) * 16];
          unsigned it = 0;
          while (__hip_atomic_load(fp, __ATOMIC_RELAXED,
                                   __HIP_MEMORY_SCOPE_AGENT) < (unsigned)p){
            if (++it > 2000000u) break;
            __builtin_amdgcn_s_sleep(1);
          }
        }
        __syncthreads();
        asm volatile("" ::: "memory");
      }
      const unsigned short* hA = h0r + (size_t)p * SLOT;
#pragma unroll
      for (int i = 0; i < 4; ++i){
        int e = tid + 256 * i;               // 0..1023 16B chunks
        int row = e >> 6, c8 = (e & 63) * 8;
        *(v4u*)&hS[row][c8] = *(const v4u*)(hA + (size_t)(m0 + row) * HID + c8);
      }
      __syncthreads();
      v4f acc = {0,0,0,0};
#pragma unroll
      for (int ks = 0; ks < 16; ++ks){
        v8bf a = *(const v8bf*)&hS[lr][ks * 32 + lk * 8];
        acc = __builtin_amdgcn_mfma_f32_16x16x32_bf16(a, wreg[ks], acc, 0, 0, 0);
      }
#pragma unroll
      for (int r = 0; r < 4; ++r)
        gbuf[w][lk * 4 + r][lr] = acc[r];
      __syncthreads();
      {
        const float* eg = embg + (size_t)tS[erow][p] + ej;
        float xi = eg[0], xf = eg[512], xg = eg[1024], xo = eg[1536];
        float ig = gbuf[0][erow][ecol] + xi, fg = gbuf[1][erow][ecol] + xf;
        float gg = gbuf[2][erow][ecol] + xg, og = gbuf[3][erow][ecol] + xo;
        float cn = sigm(fg) * creg + sigm(ig) * tanh_f(gg);
        creg = cn;
        float hn = sigm(og) * tanh_f(cn);
        unsigned short* hout = h0r + (size_t)(p + 1) * SLOT;
        unsigned v = f2bf(hn);
        unsigned pv = (unsigned)__shfl_xor((int)v, 1);
        if (!(tid & 1)){
          unsigned pack = (v & 0xFFFFu) | (pv << 16);
          __hip_atomic_store((unsigned*)(hout + (size_t)ebrow * HID + ej), pack,
                             __ATOMIC_RELAXED, __HIP_MEMORY_SCOPE_AGENT);
        }
      }
      __syncthreads();                       // drain h-stores; protect hS/gbuf
      if (tid == 0)
        __hip_atomic_store(&flags[bid * 16], (unsigned)(p + 1),
                           __ATOMIC_RELAXED, __HIP_MEMORY_SCOPE_AGENT);
    }
  } else {
    // =================== B chain: phases 1..32, PRE/CRIT split =============
    for (int p = 1; p <= 32; ++p){
      // ---- PRE: h0(p) half (A is ahead; poll is near-instant)
      if (tid < 32){
        const unsigned* fp = &flags[(band * 32 + tid) * 16];       // A flags
        unsigned it = 0;
        while (__hip_atomic_load(fp, __ATOMIC_RELAXED,
                                 __HIP_MEMORY_SCOPE_AGENT) < (unsigned)p){
          if (++it > 2000000u) break;
          __builtin_amdgcn_s_sleep(1);
        }
      }
      __syncthreads();
      asm volatile("" ::: "memory");
      const unsigned short* hA = h0r + (size_t)p * SLOT;        // h0(p)
#pragma unroll
      for (int i = 0; i < 4; ++i){
        int e = tid + 256 * i;               // 0..1023 16B chunks
        int row = e >> 6, c8 = (e & 63) * 8;
        *(v4u*)&hS[row][c8] = *(const v4u*)(hA + (size_t)(m0 + row) * HID + c8);
      }
      __syncthreads();
      v4f acc = {0,0,0,0};
#pragma unroll
      for (int ks = 0; ks < 16; ++ks){
        v8bf bf = ld8(wrow + ks * 32 + lk * 8);
        v8bf a  = *(const v8bf*)&hS[lr][ks * 32 + lk * 8];
        acc = __builtin_amdgcn_mfma_f32_16x16x32_bf16(a, bf, acc, 0, 0, 0);
      }
      // ---- CRIT: h1(p-1) half (flag visibility hidden under PRE)
      if (p >= 2){
        if (tid < 32){
          const unsigned* fp = &flags[(512 + band * 32 + tid) * 16]; // B flags
          unsigned it = 0;
          while (__hip_atomic_load(fp, __ATOMIC_RELAXED,
                                   __HIP_MEMORY_SCOPE_AGENT) < (unsigned)(p - 1)){
            if (++it > 2000000u) break;
            __builtin_amdgcn_s_sleep(1);
          }
        }
      }
      __syncthreads();
      asm volatile("" ::: "memory");
      const unsigned short* hB = h1r + (size_t)(p - 1) * SLOT;  // h1(p-1)
#pragma unroll
      for (int i = 0; i < 4; ++i){
        int e = tid + 256 * i;               // 0..1023 16B chunks
        int row = e >> 6, c8 = (e & 63) * 8;
        *(v4u*)&hS[row][512 + c8] = *(const v4u*)(hB + (size_t)(m0 + row) * HID + c8);
      }
      __syncthreads();
#pragma unroll
      for (int i = 0; i < 16; ++i){
        v8bf a = *(const v8bf*)&hS[lr][(16 + i) * 32 + lk * 8];
        acc = __builtin_amdgcn_mfma_f32_16x16x32_bf16(a, wreg[i], acc, 0, 0, 0);
      }
#pragma unroll
      for (int r = 0; r < 4; ++r)
        gbuf[w][lk * 4 + r][lr] = acc[r];
      __syncthreads();
      {
        float ig = gbuf[0][erow][ecol] + xb0, fg = gbuf[1][erow][ecol] + xb1;
        float gg = gbuf[2][erow][ecol] + xb2, og = gbuf[3][erow][ecol] + xb3;
        float cn = sigm(fg) * creg + sigm(ig) * tanh_f(gg);
        creg = cn;
        float hn = sigm(og) * tanh_f(cn);
        unsigned short* hout = h1r + (size_t)p * SLOT;          // h1(p)
        unsigned v = f2bf(hn);
        unsigned pv = (unsigned)__shfl_xor((int)v, 1);
        if (!(tid & 1)){
          unsigned pack = (v & 0xFFFFu) | (pv << 16);
          __hip_atomic_store((unsigned*)(hout + (size_t)ebrow * HID + ej), pack,
                             __ATOMIC_RELAXED, __HIP_MEMORY_SCOPE_AGENT);
        }
      }
      __syncthreads();                       // drain h-stores; protect hS/gbuf
      if (tid == 0)
        __hip_atomic_store(&flags[(512 + band * 32 + jg) * 16], (unsigned)p,
                           __ATOMIC_RELAXED, __HIP_MEMORY_SCOPE_AGENT);
    }
  }
}

// -------------------------------------- fallback: fused per-step launches ---
__global__ void __launch_bounds__(256)
k_step2(const unsigned short* __restrict__ Whh0bf,
        const unsigned short* __restrict__ Wcat1bf,
        const float* __restrict__ embg, const int* __restrict__ text,
        const float* __restrict__ b1sum,
        unsigned short* __restrict__ h0r, unsigned short* __restrict__ h1r,
        float* __restrict__ c0, float* __restrict__ c1, int p){
  const int SLOT = B_ * HID;
  const int bid = blockIdx.x;
  const bool isB = bid >= 512;
  if (isB ? (p < 1) : (p >= 32)) return;
  const int gb = bid & 511;
  const int band = gb >> 5, jg = gb & 31;
  const int m0 = band * 16, j0 = jg * 16;
  const int tid = threadIdx.x;
  const int w = tid >> 6, l = tid & 63, lr = l & 15, lk = l >> 4;
  const int t = isB ? (p - 1) : p;

  __shared__ unsigned short hS[16][1048];
  __shared__ float gbuf[4][16][17];

  const unsigned short* hA = h0r + (size_t)p * SLOT;
  const unsigned short* hB = h1r + (size_t)(isB ? (p - 1) : 0) * SLOT;

  if (isB){
#pragma unroll
    for (int i = 0; i < 8; ++i){
      int e = tid + 256 * i;
      int part = e >> 10, ei = e & 1023;
      int row = ei >> 6, c8 = (ei & 63) * 8;
      const unsigned short* src = (part ? hB : hA) + (size_t)(m0 + row) * HID + c8;
      *(v4u*)&hS[row][part * 512 + c8] = *(const v4u*)src;
    }
  } else {
#pragma unroll
    for (int i = 0; i < 4; ++i){
      int e = tid + 256 * i;
      int row = e >> 6, c8 = (e & 63) * 8;
      *(v4u*)&hS[row][c8] = *(const v4u*)(hA + (size_t)(m0 + row) * HID + c8);
    }
  }
  __syncthreads();

  const unsigned short* W = isB ? Wcat1bf : Whh0bf;
  const int wstr = isB ? 1024 : 512;
  const int KS   = isB ? 32 : 16;
  const unsigned short* wrow = W + (size_t)(w * HID + j0 + lr) * wstr;
  v4f acc = {0,0,0,0};
#pragma unroll 4
  for (int ks = 0; ks < KS; ++ks){
    const int kb = ks * 32 + lk * 8;
    v8bf a  = *(const v8bf*)&hS[lr][kb];
    v8bf bf = ld8(wrow + kb);
    acc = __builtin_amdgcn_mfma_f32_16x16x32_bf16(a, bf, acc, 0, 0, 0);
  }
#pragma unroll
  for (int r = 0; r < 4; ++r)
    gbuf[w][lk * 4 + r][lr] = acc[r];
  __syncthreads();

  {
    const int row = tid >> 4, col = tid & 15;
    const int brow = m0 + row, j = j0 + col;
    float xi, xf, xg, xo;
    if (!isB){
      const float* eg = embg + (size_t)text[brow * T_ + t] * G4 + j;
      xi = eg[0]; xf = eg[512]; xg = eg[1024]; xo = eg[1536];
    } else {
      xi = b1sum[j]; xf = b1sum[512 + j];
      xg = b1sum[1024 + j]; xo = b1sum[1536 + j];
    }
    float ig = gbuf[0][row][col] + xi, fg = gbuf[1][row][col] + xf;
    float gg = gbuf[2][row][col] + xg, og = gbuf[3][row][col] + xo;
    float* cst = isB ? c1 : c0;
    size_t ci = (size_t)brow * HID + j;
    float cn = sigm(fg) * cst[ci] + sigm(ig) * tanh_f(gg);
    cst[ci] = cn;
    float hn = sigm(og) * tanh_f(cn);
    unsigned short* hout = isB ? (h1r + (size_t)p * SLOT)
                               : (h0r + (size_t)(p + 1) * SLOT);
    unsigned v = f2bf(hn);
    unsigned pv = (unsigned)__shfl_xor((int)v, 1);
    if (!(tid & 1)){
      unsigned pack = (v & 0xFFFFu) | (pv << 16);
      *(unsigned*)(hout + (size_t)brow * HID + j) = pack;
    }
  }
}

// ----------------------------------------------------- batched attention ----
__global__ void __launch_bounds__(256)
k_attn1(const unsigned short* __restrict__ fT, const unsigned short* __restrict__ h1r,
        float* __restrict__ d_out){
  int b = blockIdx.x, tid = threadIdx.x, w = tid >> 6, l = tid & 63;
  int lr = l & 15, lk = l >> 4;
  const unsigned short* fb = fT + (size_t)b * L_ * HID;
  v4f acc[2][4] = {};
  for (int ks = 0; ks < 16; ++ks){
    int kb = ks * 32 + lk * 8;
    v8bf a0 = ld8(h1r + ((size_t)(lr + 1)  * B_ + b) * HID + kb);   // h1(lr)
    v8bf a1 = ld8(h1r + ((size_t)(lr + 17) * B_ + b) * HID + kb);   // h1(16+lr)
#pragma unroll
    for (int fn = 0; fn < 4; ++fn){
      v8bf bf = ld8(fb + (size_t)(w * 64 + fn * 16 + lr) * HID + kb);
      acc[0][fn] = __builtin_amdgcn_mfma_f32_16x16x32_bf16(a0, bf, acc[0][fn], 0, 0, 0);
      acc[1][fn] = __builtin_amdgcn_mfma_f32_16x16x32_bf16(a1, bf, acc[1][fn], 0, 0, 0);
    }
  }
#pragma unroll
  for (int fm = 0; fm < 2; ++fm)
#pragma unroll
    for (int fn = 0; fn < 4; ++fn)
#pragma unroll
      for (int r = 0; r < 4; ++r){
        int tt = fm * 16 + lk * 4 + r;
        int li = w * 64 + fn * 16 + lr;
        d_out[MASK_OFF + ((size_t)b * T_ + tt) * L_ + li] = sigm(acc[fm][fn][r]);
      }
}

__global__ void __launch_bounds__(512)
k_attn2(const unsigned short* __restrict__ fT, const float* __restrict__ d_out_ro,
        float* __restrict__ d_out, unsigned short* __restrict__ ctxbf){
  int b = blockIdx.x, tid = threadIdx.x, w = tid >> 6, l = tid & 63;
  __shared__ float aS[T_][L_];
  const float* ab = d_out_ro + MASK_OFF + (size_t)b * T_ * L_;
  for (int i = tid * 4; i < T_ * L_; i += 512 * 4){
    float4 v = *(const float4*)(ab + i);
    int tt = i >> 8, ll = i & 255;
    aS[tt][ll+0] = v.x; aS[tt][ll+1] = v.y; aS[tt][ll+2] = v.z; aS[tt][ll+3] = v.w;
  }
  __syncthreads();
  float acc[4][8] = {};
  const unsigned short* fb = fT + (size_t)b * L_ * HID + l * 8;
  for (int li = 0; li < L_; ++li){
    ushort4 u0 = *(const ushort4*)(fb + (size_t)li * HID);
    ushort4 u1 = *(const ushort4*)(fb + (size_t)li * HID + 4);
    float f[8] = {bf2f(u0.x), bf2f(u0.y), bf2f(u0.z), bf2f(u0.w),
                  bf2f(u1.x), bf2f(u1.y), bf2f(u1.z), bf2f(u1.w)};
#pragma unroll
    for (int tt = 0; tt < 4; ++tt){
      float a = aS[w * 4 + tt][li];
#pragma unroll
      for (int k = 0; k < 8; ++k) acc[tt][k] += a * f[k];
    }
  }
#pragma unroll
  for (int tt = 0; tt < 4; ++tt)
#pragma unroll
    for (int k = 0; k < 8; ++k){
      size_t o = ((size_t)b * T_ + w * 4 + tt) * HID + l * 8 + k;
      d_out[OH_OFF + o] = acc[tt][k];
      ctxbf[o] = f2bf(acc[tt][k]);
    }
}

// ------------------------------------------------------------------ final ---
__global__ void __launch_bounds__(256)
k_gen_m(const unsigned short* __restrict__ ctxbf, const unsigned short* __restrict__ genWbf,
        const float* __restrict__ genb, float* __restrict__ g){
  int m0 = blockIdx.x * 64 + (threadIdx.x >> 6) * 16;
  int j0 = blockIdx.y * 16;
  int l = threadIdx.x & 63, lr = l & 15, lk = l >> 4;
  int n = j0 + lr, nr = min(n, NC - 1);
  v4f acc = {0,0,0,0};
  for (int ks = 0; ks < 16; ++ks){
    int kb = ks * 32 + lk * 8;
    v8bf a  = ld8(ctxbf + (size_t)(m0 + lr) * HID + kb);
    v8bf bf = ld8(genWbf + (size_t)nr * HID + kb);
    acc = __builtin_amdgcn_mfma_f32_16x16x32_bf16(a, bf, acc, 0, 0, 0);
  }
  if (n < NC){
    float bb = genb[n];
#pragma unroll
    for (int r = 0; r < 4; ++r)
      g[(size_t)(m0 + lk * 4 + r) * NC + n] = acc[r] + bb;
  }
}

// --------------------------------------------------------------- fallbacks --
__global__ void __launch_bounds__(256)
k_attn_direct(const float* __restrict__ orig, const unsigned short* __restrict__ h1b,
              float* __restrict__ d_out, int t){
  int b = blockIdx.x, tid = threadIdx.x;
  __shared__ float h1s[HID];
  __shared__ float as[L_];
  h1s[tid]       = bf2f(h1b[(size_t)b * HID + tid]);
  h1s[256 + tid] = bf2f(h1b[(size_t)b * HID + 256 + tid]);
  __syncthreads();
  const float* fb = orig + (size_t)b * HID * L_;
  float dot = 0.f;
  for (int ch = 0; ch < HID; ++ch) dot += h1s[ch] * fb[(size_t)ch * L_ + tid];
  float a = sigm(dot);
  as[tid] = a;
  d_out[MASK_OFF + ((size_t)b * T_ + t) * L_ + tid] = a;
  __syncthreads();
  for (int cc = 0; cc < 2; ++cc){
    int ch = tid + cc * 256;
    float s = 0.f;
    for (int ll = 0; ll < L_; ++ll) s += as[ll] * fb[(size_t)ch * L_ + ll];
    d_out[OH_OFF + ((size_t)b * T_ + t) * HID + ch] = s;
  }
}

__global__ void k_gen_v(const float* __restrict__ ctx, const float* __restrict__ genW,
                        const float* __restrict__ genb, float* __restrict__ g){
  int o = blockIdx.x * 256 + threadIdx.x;
  if (o >= B_ * T_ * NC) return;
  int m = o / NC, n = o - m * NC;
  const float4* a = (const float4*)(ctx + (size_t)m * HID);
  const float4* wv = (const float4*)(genW + (size_t)n * HID);
  float s = genb[n];
  for (int k = 0; k < HID / 4; ++k){
    float4 av = a[k], w = wv[k];
    s += av.x * w.x + av.y * w.y + av.z * w.z + av.w * w.w;
  }
  g[o] = s;
}

// -----------------------------------------------------------------------------
extern "C" void kernel_launch(void* const* d_in, const int* in_sizes, int n_in,
                              void* d_out, int out_size, void* d_ws, size_t ws_size,
                              hipStream_t stream){
  const float* orig = (const float*)d_in[0];
  const int*   text = (const int*)  d_in[1];
  const float* embW = (const float*)d_in[2];
  const float* embb = (const float*)d_in[3];
  const float* Wih0 = (const float*)d_in[4];
  const float* Whh0 = (const float*)d_in[5];
  const float* bih0 = (const float*)d_in[6];
  const float* bhh0 = (const float*)d_in[7];
  const float* Wih1 = (const float*)d_in[8];
  const float* Whh1 = (const float*)d_in[9];
  const float* bih1 = (const float*)d_in[10];
  const float* bhh1 = (const float*)d_in[11];
  const float* genW = (const float*)d_in[12];
  const float* genb = (const float*)d_in[13];
  float* out = (float*)d_out;

  const size_t SLOTB = (size_t)B_ * HID * 2;          // 256 KB

  char* p = (char*)d_ws;
  float* embg  = (float*)p;           p += (size_t)NC * G4 * 4;
  float* b1sum = (float*)p;           p += (size_t)G4 * 4;
  // ---- zero-init region (c-state + flags) ----
  float* c0 = (float*)p;                       p += (size_t)B_ * HID * 4;
  float* c1 = (float*)p;                       p += (size_t)B_ * HID * 4;
  unsigned int* flags = (unsigned int*)p;      p += 1024 * 64;      // 1 line/block
  size_t zbytes = (size_t)((char*)p - (char*)c0);
  // ---- end zero region ----
  unsigned short* Whh0bf  = (unsigned short*)p; p += (size_t)G4 * 512 * 2;
  unsigned short* Wcat1bf = (unsigned short*)p; p += (size_t)G4 * 1024 * 2;
  unsigned short* Wih0bf  = (unsigned short*)p; p += (size_t)G4 * 512 * 2;
  unsigned short* embXbf  = (unsigned short*)p; p += (size_t)NC * HID * 2;
  unsigned short* genWbf  = (unsigned short*)p; p += (size_t)NC * HID * 2;
  unsigned short* h0r = (unsigned short*)p;    p += 34 * SLOTB;     // h0 ring (8.5MB)
  unsigned short* h1r = (unsigned short*)p;    p += 33 * SLOTB;     // h1 ring (8.25MB)
  unsigned short* ctxbf = (unsigned short*)p;  p += (size_t)B_ * T_ * HID * 2;  // 8MB
  unsigned short* fmapT = (unsigned short*)p;  p += (size_t)B_ * L_ * HID * 2;  // 64MB
  bool big = ws_size >= (size_t)(p - (char*)d_ws);

  hipMemsetAsync(c0, 0, zbytes, stream);
  hipMemsetAsync(h0r, 0, SLOTB, stream);              // h0(0) = zeros
  hipMemsetAsync(h1r, 0, SLOTB, stream);              // h1(0) = zeros

  k_wconv<<<(G4 * HID + 255) / 256, 256, 0, stream>>>(Whh0, Wih1, Whh1, Wih0,
                                                      Whh0bf, Wcat1bf, Wih0bf);
  k_small<<<(NC * HID + 255) / 256, 256, 0, stream>>>(embW, embb, genW, bih1, bhh1,
                                                      embXbf, genWbf, b1sum);
  k_embg_m<<<dim3(7, G4 / 16), 64, 0, stream>>>(embXbf, Wih0bf, bih0, bhh0, embg);
  if (big) k_fmapT<<<dim3(L_ / 32, HID / 32, B_), dim3(32, 8), 0, stream>>>(orig, fmapT);

  // ---- the recurrence: single persistent cooperative dispatch ----
  hipError_t ce = hipErrorUnknown;
  if (big){
    const unsigned short* a0 = Whh0bf; const unsigned short* a1 = Wcat1bf;
    const float* a2 = embg; const int* a3 = text; const float* a4 = b1sum;
    unsigned short* a5 = h0r; unsigned short* a6 = h1r;
    unsigned int* a7 = flags;
    void* args[] = {&a0, &a1, &a2, &a3, &a4, &a5, &a6, &a7};
    ce = hipLaunchCooperativeKernel((const void*)k_loop3, dim3(1024), dim3(256),
                                    args, 0, stream);
  }
  if (ce != hipSuccess){
    // fallback: proven 33-launch chain (round-11 path, ring buffers)
    for (int pp = 0; pp <= 32; ++pp)
      k_step2<<<1024, 256, 0, stream>>>(Whh0bf, Wcat1bf, embg, text, b1sum,
                                        h0r, h1r, c0, c1, pp);
  }

  if (big){
    k_attn1<<<B_, 256, 0, stream>>>(fmapT, h1r, out);
    k_attn2<<<B_, 512, 0, stream>>>(fmapT, (const float*)out, out, ctxbf);
    k_gen_m<<<dim3(B_ * T_ / 64, 7), 256, 0, stream>>>(ctxbf, genWbf, genb, out);
  } else {
    for (int t = 0; t < T_; ++t)
      k_attn_direct<<<B_, 256, 0, stream>>>(orig, h1r + (size_t)(t + 1) * B_ * HID,
                                            out, t);
    k_gen_v<<<(B_ * T_ * NC + 255) / 256, 256, 0, stream>>>(out + OH_OFF, genW, genb, out);
  }
}

// Round 18
// 432.316 us; speedup vs baseline: 1.0426x; 1.0027x over previous
//
#include <hip/hip_runtime.h>

#define B_   256
#define HID  512
#define T_   32
#define L_   256
#define NC   97
#define G4   2048

// d_out layout (f32): g [256,32,97] | output_hiddens [256,32,512] | masks [256,32,8,32]
#define OH_OFF   794624
#define MASK_OFF 4988928

typedef __bf16 v8bf __attribute__((ext_vector_type(8)));
typedef float  v4f  __attribute__((ext_vector_type(4)));
typedef unsigned int v4u __attribute__((ext_vector_type(4)));

__device__ __forceinline__ unsigned short f2bf(float x){
  unsigned u = __float_as_uint(x);
  u += 0x7FFFu + ((u >> 16) & 1u);          // round-to-nearest-even
  return (unsigned short)(u >> 16);
}
__device__ __forceinline__ float bf2f(unsigned short h){
  return __uint_as_float(((unsigned)h) << 16);
}
__device__ __forceinline__ float sigm(float x){ return 1.f / (1.f + __expf(-x)); }
__device__ __forceinline__ float tanh_f(float x){
  float e = __expf(2.f * x);
  return 1.f - 2.f / (e + 1.f);             // safe at +/-inf
}
__device__ __forceinline__ v8bf ld8(const unsigned short* p){
  return *reinterpret_cast<const v8bf*>(p);
}

// ---------------------------------------------------------------- one-time --
__global__ void k_wconv(const float* __restrict__ Whh0, const float* __restrict__ Wih1,
                        const float* __restrict__ Whh1, const float* __restrict__ Wih0,
                        unsigned short* __restrict__ Whh0bf, unsigned short* __restrict__ Wcat1bf,
                        unsigned short* __restrict__ Wih0bf){
  int i = blockIdx.x * 256 + threadIdx.x;
  if (i >= G4 * HID) return;
  Whh0bf[i] = f2bf(Whh0[i]);
  Wih0bf[i] = f2bf(Wih0[i]);
  int n = i >> 9, k = i & 511;
  Wcat1bf[(size_t)n * 1024 + k]       = f2bf(Wih1[i]);
  Wcat1bf[(size_t)n * 1024 + 512 + k] = f2bf(Whh1[i]);
}

__global__ void k_small(const float* __restrict__ embW, const float* __restrict__ embb,
                        const float* __restrict__ genW, const float* __restrict__ bih1,
                        const float* __restrict__ bhh1,
                        unsigned short* __restrict__ embXbf, unsigned short* __restrict__ genWbf,
                        float* __restrict__ b1sum){
  int i = blockIdx.x * 256 + threadIdx.x;
  if (i < NC * HID){
    int c = i >> 9, h = i & 511;
    embXbf[i] = f2bf(embW[h * NC + c] + embb[h]);
    genWbf[i] = f2bf(genW[i]);
  }
  if (i < G4) b1sum[i] = bih1[i] + bhh1[i];
}

// emb_gates[c][n] (MFMA, M=97 N=2048 K=512)
__global__ void __launch_bounds__(64)
k_embg_m(const unsigned short* __restrict__ embXbf, const unsigned short* __restrict__ Wih0bf,
         const float* __restrict__ bih0, const float* __restrict__ bhh0,
         float* __restrict__ embg){
  int m0 = blockIdx.x * 16, j0 = blockIdx.y * 16;
  int l = threadIdx.x, lr = l & 15, lk = l >> 4;
  int ar = min(m0 + lr, NC - 1);
  v4f acc = {0,0,0,0};
  for (int ks = 0; ks < 16; ++ks){
    int kb = ks * 32 + lk * 8;
    v8bf a  = ld8(embXbf + (size_t)ar * HID + kb);
    v8bf bf = ld8(Wih0bf + (size_t)(j0 + lr) * HID + kb);
    acc = __builtin_amdgcn_mfma_f32_16x16x32_bf16(a, bf, acc, 0, 0, 0);
  }
  int n = j0 + lr;
  float bb = bih0[n] + bhh0[n];
#pragma unroll
  for (int r = 0; r < 4; ++r){
    int c = m0 + lk * 4 + r;
    if (c < NC) embg[(size_t)c * G4 + n] = acc[r] + bb;
  }
}

// origin[b][c][l] f32 -> fmapT[b][l][c] bf16
__global__ void k_fmapT(const float* __restrict__ orig, unsigned short* __restrict__ fT){
  __shared__ float tile[32][33];
  int b = blockIdx.z, c0 = blockIdx.y * 32, l0 = blockIdx.x * 32;
  const float* src = orig + ((size_t)b * HID + c0) * L_ + l0;
  for (int i = 0; i < 32; i += 8)
    tile[threadIdx.y + i][threadIdx.x] = src[(threadIdx.y + i) * L_ + threadIdx.x];
  __syncthreads();
  unsigned short* dst = fT + ((size_t)b * L_ + l0) * HID + c0;
  for (int i = 0; i < 32; i += 8)
    dst[(threadIdx.y + i) * HID + threadIdx.x] = f2bf(tile[threadIdx.x][threadIdx.y + i]);
}

// --------------------------- persistent gate-split pipelined LSTM (coop) ----
// 1024 blocks x 256 thr, ~39KB LDS, 4 blocks/CU. Per-band direct-poll sync +
// B PRE/CRIT K-split (round 17). Round-18 changes:
//  (1) A's embg gather is phase-indexed (addresses from tS, not h-dependent):
//      issue the 4 L3 loads BEFORE the flag poll -> latency hidden under it.
//  (2) h-output stores packed 4 cols / u64 via two shfl_xor: 64 stores/block
//      instead of 128 -> halves the write-through drain ahead of the flag.
__global__ void __launch_bounds__(256, 4)
k_loop3(const unsigned short* __restrict__ Whh0bf,
        const unsigned short* __restrict__ Wcat1bf,
        const float* __restrict__ embg, const int* __restrict__ text,
        const float* __restrict__ b1sum,
        unsigned short* h0r, unsigned short* h1r,
        unsigned int* flags){
  const int SLOT = B_ * HID;
  const int bid = blockIdx.x;
  const bool isB = bid >= 512;
  const int gb = bid & 511;
  const int band = gb >> 5, jg = gb & 31;
  const int m0 = band * 16, j0 = jg * 16;
  const int tid = threadIdx.x;
  const int w = tid >> 6, l = tid & 63, lr = l & 15, lk = l >> 4;

  __shared__ unsigned short hS[16][1048];
  __shared__ float gbuf[4][16][17];
  __shared__ unsigned tS[16][32];            // text[row][t] * G4 (A blocks)

  const int erow = tid >> 4, ecol = tid & 15;      // epilogue element
  const int ebrow = m0 + erow, ej = j0 + ecol;
  float creg = 0.f;                                // c-state, 1 VGPR
  float xb0 = 0.f, xb1 = 0.f, xb2 = 0.f, xb3 = 0.f;
  if (isB){
    xb0 = b1sum[ej]; xb1 = b1sum[512 + ej];
    xb2 = b1sum[1024 + ej]; xb3 = b1sum[1536 + ej];
  } else {
    for (int e = tid; e < 512; e += 256)
      tS[e >> 5][e & 31] = (unsigned)text[(m0 + (e >> 5)) * T_ + (e & 31)] * G4;
  }
  const unsigned short* W = isB ? Wcat1bf : Whh0bf;
  const int wstr = isB ? 1024 : 512;
  const unsigned short* wrow = W + (size_t)(w * HID + j0 + lr) * wstr;

  // ---- hoist phase-invariant weights (A: all 16 ks; B: crit half ks 16..31)
  v8bf wreg[16];
  if (!isB){
#pragma unroll
    for (int i = 0; i < 16; ++i) wreg[i] = ld8(wrow + i * 32 + lk * 8);
  } else {
#pragma unroll
    for (int i = 0; i < 16; ++i) wreg[i] = ld8(wrow + (16 + i) * 32 + lk * 8);
  }
  __syncthreads();                           // tS visible before phase-0 reads

  if (!isB){
    // =================== A chain: phases 0..31 =============================
    for (int p = 0; p < 32; ++p){
      // early-issue embg gather (phase-indexed, h-independent): its L3
      // latency hides under the flag poll + staging below.
      const float* eg = embg + (size_t)tS[erow][p] + ej;
      float xi = eg[0], xf = eg[512], xg = eg[1024], xo = eg[1536];
      if (p >= 1){
        if (tid < 32){
          const unsigned* fp = &flags[(band * 32 + tid) * 16];
          unsigned it = 0;
          while (__hip_atomic_load(fp, __ATOMIC_RELAXED,
                                   __HIP_MEMORY_SCOPE_AGENT) < (unsigned)p){
            if (++it > 2000000u) break;
            __builtin_amdgcn_s_sleep(1);
          }
        }
        __syncthreads();
        asm volatile("" ::: "memory");
      }
      const unsigned short* hA = h0r + (size_t)p * SLOT;
#pragma unroll
      for (int i = 0; i < 4; ++i){
        int e = tid + 256 * i;               // 0..1023 16B chunks
        int row = e >> 6, c8 = (e & 63) * 8;
        *(v4u*)&hS[row][c8] = *(const v4u*)(hA + (size_t)(m0 + row) * HID + c8);
      }
      __syncthreads();
      v4f acc = {0,0,0,0};
#pragma unroll
      for (int ks = 0; ks < 16; ++ks){
        v8bf a = *(const v8bf*)&hS[lr][ks * 32 + lk * 8];
        acc = __builtin_amdgcn_mfma_f32_16x16x32_bf16(a, wreg[ks], acc, 0, 0, 0);
      }
#pragma unroll
      for (int r = 0; r < 4; ++r)
        gbuf[w][lk * 4 + r][lr] = acc[r];
      __syncthreads();
      {
        float ig = gbuf[0][erow][ecol] + xi, fg = gbuf[1][erow][ecol] + xf;
        float gg = gbuf[2][erow][ecol] + xg, og = gbuf[3][erow][ecol] + xo;
        float cn = sigm(fg) * creg + sigm(ig) * tanh_f(gg);
        creg = cn;
        float hn = sigm(og) * tanh_f(cn);
        unsigned short* hout = h0r + (size_t)(p + 1) * SLOT;
        unsigned v = f2bf(hn);
        unsigned pv = (unsigned)__shfl_xor((int)v, 1);
        unsigned pack01 = (v & 0xFFFFu) | (pv << 16);            // cols c,c+1
        unsigned pack23 = (unsigned)__shfl_xor((int)pack01, 2);  // cols c+2,c+3
        if (!(tid & 3)){
          unsigned long long pk = (unsigned long long)pack01
                                | ((unsigned long long)pack23 << 32);
          __hip_atomic_store((unsigned long long*)(hout + (size_t)ebrow * HID + ej),
                             pk, __ATOMIC_RELAXED, __HIP_MEMORY_SCOPE_AGENT);
        }
      }
      __syncthreads();                       // drain h-stores; protect hS/gbuf
      if (tid == 0)
        __hip_atomic_store(&flags[bid * 16], (unsigned)(p + 1),
                           __ATOMIC_RELAXED, __HIP_MEMORY_SCOPE_AGENT);
    }
  } else {
    // =================== B chain: phases 1..32, PRE/CRIT split =============
    for (int p = 1; p <= 32; ++p){
      // ---- PRE: h0(p) half (A is ahead; poll is near-instant)
      if (tid < 32){
        const unsigned* fp = &flags[(band * 32 + tid) * 16];       // A flags
        unsigned it = 0;
        while (__hip_atomic_load(fp, __ATOMIC_RELAXED,
                                 __HIP_MEMORY_SCOPE_AGENT) < (unsigned)p){
          if (++it > 2000000u) break;
          __builtin_amdgcn_s_sleep(1);
        }
      }
      __syncthreads();
      asm volatile("" ::: "memory");
      const unsigned short* hA = h0r + (size_t)p * SLOT;        // h0(p)
#pragma unroll
      for (int i = 0; i < 4; ++i){
        int e = tid + 256 * i;               // 0..1023 16B chunks
        int row = e >> 6, c8 = (e & 63) * 8;
        *(v4u*)&hS[row][c8] = *(const v4u*)(hA + (size_t)(m0 + row) * HID + c8);
      }
      __syncthreads();
      v4f acc = {0,0,0,0};
#pragma unroll
      for (int ks = 0; ks < 16; ++ks){
        v8bf bf = ld8(wrow + ks * 32 + lk * 8);
        v8bf a  = *(const v8bf*)&hS[lr][ks * 32 + lk * 8];
        acc = __builtin_amdgcn_mfma_f32_16x16x32_bf16(a, bf, acc, 0, 0, 0);
      }
      // ---- CRIT: h1(p-1) half (flag visibility hidden under PRE)
      if (p >= 2){
        if (tid < 32){
          const unsigned* fp = &flags[(512 + band * 32 + tid) * 16]; // B flags
          unsigned it = 0;
          while (__hip_atomic_load(fp, __ATOMIC_RELAXED,
                                   __HIP_MEMORY_SCOPE_AGENT) < (unsigned)(p - 1)){
            if (++it > 2000000u) break;
            __builtin_amdgcn_s_sleep(1);
          }
        }
      }
      __syncthreads();
      asm volatile("" ::: "memory");
      const unsigned short* hB = h1r + (size_t)(p - 1) * SLOT;  // h1(p-1)
#pragma unroll
      for (int i = 0; i < 4; ++i){
        int e = tid + 256 * i;               // 0..1023 16B chunks
        int row = e >> 6, c8 = (e & 63) * 8;
        *(v4u*)&hS[row][512 + c8] = *(const v4u*)(hB + (size_t)(m0 + row) * HID + c8);
      }
      __syncthreads();
#pragma unroll
      for (int i = 0; i < 16; ++i){
        v8bf a = *(const v8bf*)&hS[lr][(16 + i) * 32 + lk * 8];
        acc = __builtin_amdgcn_mfma_f32_16x16x32_bf16(a, wreg[i], acc, 0, 0, 0);
      }
#pragma unroll
      for (int r = 0; r < 4; ++r)
        gbuf[w][lk * 4 + r][lr] = acc[r];
      __syncthreads();
      {
        float ig = gbuf[0][erow][ecol] + xb0, fg = gbuf[1][erow][ecol] + xb1;
        float gg = gbuf[2][erow][ecol] + xb2, og = gbuf[3][erow][ecol] + xb3;
        float cn = sigm(fg) * creg + sigm(ig) * tanh_f(gg);
        creg = cn;
        float hn = sigm(og) * tanh_f(cn);
        unsigned short* hout = h1r + (size_t)p * SLOT;          // h1(p)
        unsigned v = f2bf(hn);
        unsigned pv = (unsigned)__shfl_xor((int)v, 1);
        unsigned pack01 = (v & 0xFFFFu) | (pv << 16);
        unsigned pack23 = (unsigned)__shfl_xor((int)pack01, 2);
        if (!(tid & 3)){
          unsigned long long pk = (unsigned long long)pack01
                                | ((unsigned long long)pack23 << 32);
          __hip_atomic_store((unsigned long long*)(hout + (size_t)ebrow * HID + ej),
                             pk, __ATOMIC_RELAXED, __HIP_MEMORY_SCOPE_AGENT);
        }
      }
      __syncthreads();                       // drain h-stores; protect hS/gbuf
      if (tid == 0)
        __hip_atomic_store(&flags[(512 + band * 32 + jg) * 16], (unsigned)p,
                           __ATOMIC_RELAXED, __HIP_MEMORY_SCOPE_AGENT);
    }
  }
}

// -------------------------------------- fallback: fused per-step launches ---
__global__ void __launch_bounds__(256)
k_step2(const unsigned short* __restrict__ Whh0bf,
        const unsigned short* __restrict__ Wcat1bf,
        const float* __restrict__ embg, const int* __restrict__ text,
        const float* __restrict__ b1sum,
        unsigned short* __restrict__ h0r, unsigned short* __restrict__ h1r,
        float* __restrict__ c0, float* __restrict__ c1, int p){
  const int SLOT = B_ * HID;
  const int bid = blockIdx.x;
  const bool isB = bid >= 512;
  if (isB ? (p < 1) : (p >= 32)) return;
  const int gb = bid & 511;
  const int band = gb >> 5, jg = gb & 31;
  const int m0 = band * 16, j0 = jg * 16;
  const int tid = threadIdx.x;
  const int w = tid >> 6, l = tid & 63, lr = l & 15, lk = l >> 4;
  const int t = isB ? (p - 1) : p;

  __shared__ unsigned short hS[16][1048];
  __shared__ float gbuf[4][16][17];

  const unsigned short* hA = h0r + (size_t)p * SLOT;
  const unsigned short* hB = h1r + (size_t)(isB ? (p - 1) : 0) * SLOT;

  if (isB){
#pragma unroll
    for (int i = 0; i < 8; ++i){
      int e = tid + 256 * i;
      int part = e >> 10, ei = e & 1023;
      int row = ei >> 6, c8 = (ei & 63) * 8;
      const unsigned short* src = (part ? hB : hA) + (size_t)(m0 + row) * HID + c8;
      *(v4u*)&hS[row][part * 512 + c8] = *(const v4u*)src;
    }
  } else {
#pragma unroll
    for (int i = 0; i < 4; ++i){
      int e = tid + 256 * i;
      int row = e >> 6, c8 = (e & 63) * 8;
      *(v4u*)&hS[row][c8] = *(const v4u*)(hA + (size_t)(m0 + row) * HID + c8);
    }
  }
  __syncthreads();

  const unsigned short* W = isB ? Wcat1bf : Whh0bf;
  const int wstr = isB ? 1024 : 512;
  const int KS   = isB ? 32 : 16;
  const unsigned short* wrow = W + (size_t)(w * HID + j0 + lr) * wstr;
  v4f acc = {0,0,0,0};
#pragma unroll 4
  for (int ks = 0; ks < KS; ++ks){
    const int kb = ks * 32 + lk * 8;
    v8bf a  = *(const v8bf*)&hS[lr][kb];
    v8bf bf = ld8(wrow + kb);
    acc = __builtin_amdgcn_mfma_f32_16x16x32_bf16(a, bf, acc, 0, 0, 0);
  }
#pragma unroll
  for (int r = 0; r < 4; ++r)
    gbuf[w][lk * 4 + r][lr] = acc[r];
  __syncthreads();

  {
    const int row = tid >> 4, col = tid & 15;
    const int brow = m0 + row, j = j0 + col;
    float xi, xf, xg, xo;
    if (!isB){
      const float* eg = embg + (size_t)text[brow * T_ + t] * G4 + j;
      xi = eg[0]; xf = eg[512]; xg = eg[1024]; xo = eg[1536];
    } else {
      xi = b1sum[j]; xf = b1sum[512 + j];
      xg = b1sum[1024 + j]; xo = b1sum[1536 + j];
    }
    float ig = gbuf[0][row][col] + xi, fg = gbuf[1][row][col] + xf;
    float gg = gbuf[2][row][col] + xg, og = gbuf[3][row][col] + xo;
    float* cst = isB ? c1 : c0;
    size_t ci = (size_t)brow * HID + j;
    float cn = sigm(fg) * cst[ci] + sigm(ig) * tanh_f(gg);
    cst[ci] = cn;
    float hn = sigm(og) * tanh_f(cn);
    unsigned short* hout = isB ? (h1r + (size_t)p * SLOT)
                               : (h0r + (size_t)(p + 1) * SLOT);
    unsigned v = f2bf(hn);
    unsigned pv = (unsigned)__shfl_xor((int)v, 1);
    if (!(tid & 1)){
      unsigned pack = (v & 0xFFFFu) | (pv << 16);
      *(unsigned*)(hout + (size_t)brow * HID + j) = pack;
    }
  }
}

// ----------------------------------------------------- batched attention ----
__global__ void __launch_bounds__(256)
k_attn1(const unsigned short* __restrict__ fT, const unsigned short* __restrict__ h1r,
        float* __restrict__ d_out){
  int b = blockIdx.x, tid = threadIdx.x, w = tid >> 6, l = tid & 63;
  int lr = l & 15, lk = l >> 4;
  const unsigned short* fb = fT + (size_t)b * L_ * HID;
  v4f acc[2][4] = {};
  for (int ks = 0; ks < 16; ++ks){
    int kb = ks * 32 + lk * 8;
    v8bf a0 = ld8(h1r + ((size_t)(lr + 1)  * B_ + b) * HID + kb);   // h1(lr)
    v8bf a1 = ld8(h1r + ((size_t)(lr + 17) * B_ + b) * HID + kb);   // h1(16+lr)
#pragma unroll
    for (int fn = 0; fn < 4; ++fn){
      v8bf bf = ld8(fb + (size_t)(w * 64 + fn * 16 + lr) * HID + kb);
      acc[0][fn] = __builtin_amdgcn_mfma_f32_16x16x32_bf16(a0, bf, acc[0][fn], 0, 0, 0);
      acc[1][fn] = __builtin_amdgcn_mfma_f32_16x16x32_bf16(a1, bf, acc[1][fn], 0, 0, 0);
    }
  }
#pragma unroll
  for (int fm = 0; fm < 2; ++fm)
#pragma unroll
    for (int fn = 0; fn < 4; ++fn)
#pragma unroll
      for (int r = 0; r < 4; ++r){
        int tt = fm * 16 + lk * 4 + r;
        int li = w * 64 + fn * 16 + lr;
        d_out[MASK_OFF + ((size_t)b * T_ + tt) * L_ + li] = sigm(acc[fm][fn][r]);
      }
}

__global__ void __launch_bounds__(512)
k_attn2(const unsigned short* __restrict__ fT, const float* __restrict__ d_out_ro,
        float* __restrict__ d_out, unsigned short* __restrict__ ctxbf){
  int b = blockIdx.x, tid = threadIdx.x, w = tid >> 6, l = tid & 63;
  __shared__ float aS[T_][L_];
  const float* ab = d_out_ro + MASK_OFF + (size_t)b * T_ * L_;
  for (int i = tid * 4; i < T_ * L_; i += 512 * 4){
    float4 v = *(const float4*)(ab + i);
    int tt = i >> 8, ll = i & 255;
    aS[tt][ll+0] = v.x; aS[tt][ll+1] = v.y; aS[tt][ll+2] = v.z; aS[tt][ll+3] = v.w;
  }
  __syncthreads();
  float acc[4][8] = {};
  const unsigned short* fb = fT + (size_t)b * L_ * HID + l * 8;
  for (int li = 0; li < L_; ++li){
    ushort4 u0 = *(const ushort4*)(fb + (size_t)li * HID);
    ushort4 u1 = *(const ushort4*)(fb + (size_t)li * HID + 4);
    float f[8] = {bf2f(u0.x), bf2f(u0.y), bf2f(u0.z), bf2f(u0.w),
                  bf2f(u1.x), bf2f(u1.y), bf2f(u1.z), bf2f(u1.w)};
#pragma unroll
    for (int tt = 0; tt < 4; ++tt){
      float a = aS[w * 4 + tt][li];
#pragma unroll
      for (int k = 0; k < 8; ++k) acc[tt][k] += a * f[k];
    }
  }
#pragma unroll
  for (int tt = 0; tt < 4; ++tt)
#pragma unroll
    for (int k = 0; k < 8; ++k){
      size_t o = ((size_t)b * T_ + w * 4 + tt) * HID + l * 8 + k;
      d_out[OH_OFF + o] = acc[tt][k];
      ctxbf[o] = f2bf(acc[tt][k]);
    }
}

// ------------------------------------------------------------------ final ---
__global__ void __launch_bounds__(256)
k_gen_m(const unsigned short* __restrict__ ctxbf, const unsigned short* __restrict__ genWbf,
        const float* __restrict__ genb, float* __restrict__ g){
  int m0 = blockIdx.x * 64 + (threadIdx.x >> 6) * 16;
  int j0 = blockIdx.y * 16;
  int l = threadIdx.x & 63, lr = l & 15, lk = l >> 4;
  int n = j0 + lr, nr = min(n, NC - 1);
  v4f acc = {0,0,0,0};
  for (int ks = 0; ks < 16; ++ks){
    int kb = ks * 32 + lk * 8;
    v8bf a  = ld8(ctxbf + (size_t)(m0 + lr) * HID + kb);
    v8bf bf = ld8(genWbf + (size_t)nr * HID + kb);
    acc = __builtin_amdgcn_mfma_f32_16x16x32_bf16(a, bf, acc, 0, 0, 0);
  }
  if (n < NC){
    float bb = genb[n];
#pragma unroll
    for (int r = 0; r < 4; ++r)
      g[(size_t)(m0 + lk * 4 + r) * NC + n] = acc[r] + bb;
  }
}

// --------------------------------------------------------------- fallbacks --
__global__ void __launch_bounds__(256)
k_attn_direct(const float* __restrict__ orig, const unsigned short* __restrict__ h1b,
              float* __restrict__ d_out, int t){
  int b = blockIdx.x, tid = threadIdx.x;
  __shared__ float h1s[HID];
  __shared__ float as[L_];
  h1s[tid]       = bf2f(h1b[(size_t)b * HID + tid]);
  h1s[256 + tid] = bf2f(h1b[(size_t)b * HID + 256 + tid]);
  __syncthreads();
  const float* fb = orig + (size_t)b * HID * L_;
  float dot = 0.f;
  for (int ch = 0; ch < HID; ++ch) dot += h1s[ch] * fb[(size_t)ch * L_ + tid];
  float a = sigm(dot);
  as[tid] = a;
  d_out[MASK_OFF + ((size_t)b * T_ + t) * L_ + tid] = a;
  __syncthreads();
  for (int cc = 0; cc < 2; ++cc){
    int ch = tid + cc * 256;
    float s = 0.f;
    for (int ll = 0; ll < L_; ++ll) s += as[ll] * fb[(size_t)ch * L_ + ll];
    d_out[OH_OFF + ((size_t)b * T_ + t) * HID + ch] = s;
  }
}

__global__ void k_gen_v(const float* __restrict__ ctx, const float* __restrict__ genW,
                        const float* __restrict__ genb, float* __restrict__ g){
  int o = blockIdx.x * 256 + threadIdx.x;
  if (o >= B_ * T_ * NC) return;
  int m = o / NC, n = o - m * NC;
  const float4* a = (const float4*)(ctx + (size_t)m * HID);
  const float4* wv = (const float4*)(genW + (size_t)n * HID);
  float s = genb[n];
  for (int k = 0; k < HID / 4; ++k){
    float4 av = a[k], w = wv[k];
    s += av.x * w.x + av.y * w.y + av.z * w.z + av.w * w.w;
  }
  g[o] = s;
}

// -----------------------------------------------------------------------------
extern "C" void kernel_launch(void* const* d_in, const int* in_sizes, int n_in,
                              void* d_out, int out_size, void* d_ws, size_t ws_size,
                              hipStream_t stream){
  const float* orig = (const float*)d_in[0];
  const int*   text = (const int*)  d_in[1];
  const float* embW = (const float*)d_in[2];
  const float* embb = (const float*)d_in[3];
  const float* Wih0 = (const float*)d_in[4];
  const float* Whh0 = (const float*)d_in[5];
  const float* bih0 = (const float*)d_in[6];
  const float* bhh0 = (const float*)d_in[7];
  const float* Wih1 = (const float*)d_in[8];
  const float* Whh1 = (const float*)d_in[9];
  const float* bih1 = (const float*)d_in[10];
  const float* bhh1 = (const float*)d_in[11];
  const float* genW = (const float*)d_in[12];
  const float* genb = (const float*)d_in[13];
  float* out = (float*)d_out;

  const size_t SLOTB = (size_t)B_ * HID * 2;          // 256 KB

  char* p = (char*)d_ws;
  float* embg  = (float*)p;           p += (size_t)NC * G4 * 4;
  float* b1sum = (float*)p;           p += (size_t)G4 * 4;
  // ---- zero-init region (c-state + flags) ----
  float* c0 = (float*)p;                       p += (size_t)B_ * HID * 4;
  float* c1 = (float*)p;                       p += (size_t)B_ * HID * 4;
  unsigned int* flags = (unsigned int*)p;      p += 1024 * 64;      // 1 line/block
  size_t zbytes = (size_t)((char*)p - (char*)c0);
  // ---- end zero region ----
  unsigned short* Whh0bf  = (unsigned short*)p; p += (size_t)G4 * 512 * 2;
  unsigned short* Wcat1bf = (unsigned short*)p; p += (size_t)G4 * 1024 * 2;
  unsigned short* Wih0bf  = (unsigned short*)p; p += (size_t)G4 * 512 * 2;
  unsigned short* embXbf  = (unsigned short*)p; p += (size_t)NC * HID * 2;
  unsigned short* genWbf  = (unsigned short*)p; p += (size_t)NC * HID * 2;
  unsigned short* h0r = (unsigned short*)p;    p += 34 * SLOTB;     // h0 ring (8.5MB)
  unsigned short* h1r = (unsigned short*)p;    p += 33 * SLOTB;     // h1 ring (8.25MB)
  unsigned short* ctxbf = (unsigned short*)p;  p += (size_t)B_ * T_ * HID * 2;  // 8MB
  unsigned short* fmapT = (unsigned short*)p;  p += (size_t)B_ * L_ * HID * 2;  // 64MB
  bool big = ws_size >= (size_t)(p - (char*)d_ws);

  hipMemsetAsync(c0, 0, zbytes, stream);
  hipMemsetAsync(h0r, 0, SLOTB, stream);              // h0(0) = zeros
  hipMemsetAsync(h1r, 0, SLOTB, stream);              // h1(0) = zeros

  k_wconv<<<(G4 * HID + 255) / 256, 256, 0, stream>>>(Whh0, Wih1, Whh1, Wih0,
                                                      Whh0bf, Wcat1bf, Wih0bf);
  k_small<<<(NC * HID + 255) / 256, 256, 0, stream>>>(embW, embb, genW, bih1, bhh1,
                                                      embXbf, genWbf, b1sum);
  k_embg_m<<<dim3(7, G4 / 16), 64, 0, stream>>>(embXbf, Wih0bf, bih0, bhh0, embg);
  if (big) k_fmapT<<<dim3(L_ / 32, HID / 32, B_), dim3(32, 8), 0, stream>>>(orig, fmapT);

  // ---- the recurrence: single persistent cooperative dispatch ----
  hipError_t ce = hipErrorUnknown;
  if (big){
    const unsigned short* a0 = Whh0bf; const unsigned short* a1 = Wcat1bf;
    const float* a2 = embg; const int* a3 = text; const float* a4 = b1sum;
    unsigned short* a5 = h0r; unsigned short* a6 = h1r;
    unsigned int* a7 = flags;
    void* args[] = {&a0, &a1, &a2, &a3, &a4, &a5, &a6, &a7};
    ce = hipLaunchCooperativeKernel((const void*)k_loop3, dim3(1024), dim3(256),
                                    args, 0, stream);
  }
  if (ce != hipSuccess){
    // fallback: proven 33-launch chain (round-11 path, ring buffers)
    for (int pp = 0; pp <= 32; ++pp)
      k_step2<<<1024, 256, 0, stream>>>(Whh0bf, Wcat1bf, embg, text, b1sum,
                                        h0r, h1r, c0, c1, pp);
  }

  if (big){
    k_attn1<<<B_, 256, 0, stream>>>(fmapT, h1r, out);
    k_attn2<<<B_, 512, 0, stream>>>(fmapT, (const float*)out, out, ctxbf);
    k_gen_m<<<dim3(B_ * T_ / 64, 7), 256, 0, stream>>>(ctxbf, genWbf, genb, out);
  } else {
    for (int t = 0; t < T_; ++t)
      k_attn_direct<<<B_, 256, 0, stream>>>(orig, h1r + (size_t)(t + 1) * B_ * HID,
                                            out, t);
    k_gen_v<<<(B_ * T_ * NC + 255) / 256, 256, 0, stream>>>(out + OH_OFF, genW, genb, out);
  }
}